// Round 10
// baseline (995.071 us; speedup 1.0000x reference)
//
#include <hip/hip_runtime.h>
#include <stdint.h>

#define N_NODES 100000
#define N_EDGES 1600000
#define EAD 7
#define H 64
#define LAT 32
#define NG 512
#define NC 6

#define C1F 100                 // nodes per block, conv1_fused (100000/100=1000 blocks)
#define C2F 100                 // nodes per block, conv2_fused
#define HD_NPB 64
#define NZ (N_NODES * LAT)
#define F4_PER_ARR (NZ / 4)
#define NBLK ((N_NODES + 255) / 256)   // 391 scan blocks

static_assert(N_NODES % C1F == 0 && C1F % 4 == 0, "conv1 grid exact");
static_assert(N_NODES % C2F == 0 && C2F % 4 == 0, "conv2 grid exact");
static_assert(N_EDGES % 256 == 0, "edge grid exact");
static_assert(NBLK <= 512, "scan_partials capacity");

// ---------------- Threefry-2x32-20, key = (0, 42) ---------------------------
__device__ __forceinline__ void threefry2x32_42(uint32_t& x0, uint32_t& x1) {
    const uint32_t k0 = 0u, k1 = 42u;
    const uint32_t k2 = k0 ^ k1 ^ 0x1BD11BDAu;
    x0 += k0; x1 += k1;
#define TF_ROUND(r) { x0 += x1; x1 = (x1 << (r)) | (x1 >> (32 - (r))); x1 ^= x0; }
    TF_ROUND(13) TF_ROUND(15) TF_ROUND(26) TF_ROUND(6)
    x0 += k1; x1 += k2 + 1u;
    TF_ROUND(17) TF_ROUND(29) TF_ROUND(16) TF_ROUND(24)
    x0 += k2; x1 += k0 + 2u;
    TF_ROUND(13) TF_ROUND(15) TF_ROUND(26) TF_ROUND(6)
    x0 += k0; x1 += k1 + 3u;
    TF_ROUND(17) TF_ROUND(29) TF_ROUND(16) TF_ROUND(24)
    x0 += k1; x1 += k2 + 4u;
    TF_ROUND(13) TF_ROUND(15) TF_ROUND(26) TF_ROUND(6)
    x0 += k2; x1 += k0 + 5u;
#undef TF_ROUND
}

// XLA f32 ErfInv (Giles)
__device__ __forceinline__ float erfinv_f32(float x) {
    float w = -log1pf(-x * x);
    float p;
    if (w < 5.0f) {
        w = w - 2.5f;
        p = 2.81022636e-08f;
        p = fmaf(p, w, 3.43273939e-07f);
        p = fmaf(p, w, -3.5233877e-06f);
        p = fmaf(p, w, -4.39150654e-06f);
        p = fmaf(p, w, 0.00021858087f);
        p = fmaf(p, w, -0.00125372503f);
        p = fmaf(p, w, -0.00417768164f);
        p = fmaf(p, w, 0.246640727f);
        p = fmaf(p, w, 1.50140941f);
    } else {
        w = sqrtf(w) - 3.0f;
        p = -0.000200214257f;
        p = fmaf(p, w, 0.000100950558f);
        p = fmaf(p, w, 0.00134934322f);
        p = fmaf(p, w, -0.00367342844f);
        p = fmaf(p, w, 0.00573950773f);
        p = fmaf(p, w, -0.0076224613f);
        p = fmaf(p, w, 0.00943887047f);
        p = fmaf(p, w, 1.00167406f);
        p = fmaf(p, w, 2.83297682f);
    }
    return p * x;
}

// ================= CSR build: histogram -> scan -> fill =====================
__global__ void csr_count(const int* __restrict__ dst, int* __restrict__ deg) {
    int e = blockIdx.x * blockDim.x + threadIdx.x;
    if (e < N_EDGES) atomicAdd(&deg[dst[e]], 1);
}

__global__ void scan_bsums(const int* __restrict__ deg, int* __restrict__ bsum) {
    __shared__ int s[256];
    int t = threadIdx.x, i = blockIdx.x * 256 + t;
    s[t] = (i < N_NODES) ? deg[i] : 0;
    __syncthreads();
    for (int off = 128; off > 0; off >>= 1) {
        if (t < off) s[t] += s[t + off];
        __syncthreads();
    }
    if (t == 0) bsum[blockIdx.x] = s[0];
}

// single block of 512: overwrite bsum with its EXCLUSIVE prefix
__global__ void scan_partials(int* __restrict__ bsum) {
    __shared__ int s[512];
    int t = threadIdx.x;
    int v = (t < NBLK) ? bsum[t] : 0;
    s[t] = v;
    __syncthreads();
    for (int off = 1; off < 512; off <<= 1) {
        int add = (t >= off) ? s[t - off] : 0;
        __syncthreads();
        s[t] += add;
        __syncthreads();
    }
    if (t < NBLK) bsum[t] = s[t] - v;   // exclusive
}

__global__ void scan_base(const int* __restrict__ deg, const int* __restrict__ bsum,
                          int* __restrict__ base) {
    __shared__ int s[256];
    int t = threadIdx.x, i = blockIdx.x * 256 + t;
    int v = (i < N_NODES) ? deg[i] : 0;
    s[t] = v;
    __syncthreads();
    for (int off = 1; off < 256; off <<= 1) {
        int add = (t >= off) ? s[t - off] : 0;
        __syncthreads();
        s[t] += add;
        __syncthreads();
    }
    if (i < N_NODES) base[i] = bsum[blockIdx.x] + s[t] - v;   // exclusive
}

// after fill, base[n] == end(n); start = base[n] - deg[n]
__global__ void csr_fill(const int* __restrict__ dst, int* __restrict__ base,
                         int* __restrict__ eids) {
    int e = blockIdx.x * blockDim.x + threadIdx.x;
    if (e < N_EDGES) {
        int slot = atomicAdd(&base[dst[e]], 1);
        eids[slot] = e;
    }
}

// ================= conv1 fused: CSR gather + MLP 1->64->64 ==================
__global__ void conv1_fused(const float* __restrict__ x, const int* __restrict__ src,
                            const float* __restrict__ ea, const int* __restrict__ eids,
                            const int* __restrict__ base, const int* __restrict__ deg,
                            const float* __restrict__ We1, const float* __restrict__ be1,
                            const float* __restrict__ W11, const float* __restrict__ b11,
                            const float* __restrict__ W12, const float* __restrict__ b12,
                            const float* __restrict__ eps1, float* __restrict__ hout) {
    __shared__ float sW12[H * H];
    __shared__ float st[4][H];
    int tid = threadIdx.x;
    for (int i = tid; i < H * H; i += 256) sW12[i] = W12[i];
    int sub = tid >> 6, lane = tid & 63;
    float eps = eps1[0], be1s = be1[0];
    float we1r[EAD];
#pragma unroll
    for (int j = 0; j < EAD; j++) we1r[j] = We1[j];
    float w11 = W11[lane], bb11 = b11[lane], bb12 = b12[lane];
    __syncthreads();
    for (int it = 0; it < C1F / 4; it++) {
        int n = blockIdx.x * C1F + it * 4 + sub;
        int cnt = deg[n], s0 = base[n] - cnt;
        float part = 0.0f;
        for (int k = lane; k < cnt; k += 64) {
            int e = eids[s0 + k];
            float proj = be1s;
#pragma unroll
            for (int j = 0; j < EAD; j++) proj = fmaf(ea[e * EAD + j], we1r[j], proj);
            float m = x[src[e]] + proj;
            part += fmaxf(m, 0.0f);
        }
#pragma unroll
        for (int off = 1; off < 64; off <<= 1) part += __shfl_xor(part, off, 64);
        float xn = x[n];
        float h1 = fmaf(eps, xn, xn) + part;
        float t = fmaf(h1, w11, bb11);
        st[sub][lane] = t > 0.0f ? t : 0.0f;
        __syncthreads();
        float acc = bb12;
#pragma unroll
        for (int j = 0; j < H; j++) acc = fmaf(st[sub][j], sW12[j * H + lane], acc);
        hout[(size_t)n * H + lane] = acc > 0.0f ? acc : 0.0f;
        __syncthreads();
    }
}

// ================= conv2 fused: CSR gather (reg acc) + MLP 64->64->64 =======
// reads hA (stable), writes hB — no atomics, no agg2 array
__global__ void conv2_fused(const float* __restrict__ hA, const int* __restrict__ src,
                            const float* __restrict__ ea, const int* __restrict__ eids,
                            const int* __restrict__ base, const int* __restrict__ deg,
                            const float* __restrict__ We2, const float* __restrict__ be2,
                            const float* __restrict__ W21, const float* __restrict__ b21,
                            const float* __restrict__ W22, const float* __restrict__ b22,
                            const float* __restrict__ eps2, float* __restrict__ hB) {
    __shared__ float sW21[H * H], sW22[H * H];
    __shared__ float sh2[4][H], st[4][H];
    int tid = threadIdx.x;
    for (int i = tid; i < H * H; i += 256) { sW21[i] = W21[i]; sW22[i] = W22[i]; }
    int sub = tid >> 6, lane = tid & 63;
    float epsv = eps2[0];
    float we2r[EAD];
#pragma unroll
    for (int j = 0; j < EAD; j++) we2r[j] = We2[j * H + lane];
    float be2r = be2[lane], bb21 = b21[lane], bb22 = b22[lane];
    __syncthreads();
    for (int it = 0; it < C2F / 4; it++) {
        int n = blockIdx.x * C2F + it * 4 + sub;
        int cnt = deg[n], s0 = base[n] - cnt;
        float agg = 0.0f;
        for (int k = 0; k < cnt; k++) {
            int e = eids[s0 + k];                   // uniform -> broadcast
            int s = src[e];                         // uniform -> broadcast
            float proj = be2r;
#pragma unroll
            for (int j = 0; j < EAD; j++) proj = fmaf(ea[e * EAD + j], we2r[j], proj);
            float m = hA[(size_t)s * H + lane] + proj;   // coalesced 256B
            agg += fmaxf(m, 0.0f);
        }
        float hv = hA[(size_t)n * H + lane];
        sh2[sub][lane] = fmaf(epsv, hv, hv) + agg;
        __syncthreads();
        float acc = bb21;
#pragma unroll
        for (int j = 0; j < H; j++) acc = fmaf(sh2[sub][j], sW21[j * H + lane], acc);
        st[sub][lane] = acc > 0.0f ? acc : 0.0f;
        __syncthreads();
        acc = bb22;
#pragma unroll
        for (int j = 0; j < H; j++) acc = fmaf(st[sub][j], sW22[j * H + lane], acc);
        hB[(size_t)n * H + lane] = acc > 0.0f ? acc : 0.0f;
        __syncthreads();
    }
}

// ================= heads part 1: mu/logvar GEMVs -> d_ws ====================
__global__ void heads_ml(const float* __restrict__ h,
                         const float* __restrict__ Wmu, const float* __restrict__ bmu,
                         const float* __restrict__ Wlv, const float* __restrict__ blv,
                         float* __restrict__ muws, float* __restrict__ lvws) {
    __shared__ float sWmu[H * LAT], sWlv[H * LAT];
    __shared__ float sh[8][H];
    int tid = threadIdx.x;
    for (int i = tid; i < H * LAT; i += 256) { sWmu[i] = Wmu[i]; sWlv[i] = Wlv[i]; }
    int sub = tid >> 5, lane = tid & 31;
    float bbmu = bmu[lane], bblv = blv[lane];
    __syncthreads();
    for (int it = 0; it < HD_NPB / 8; it++) {
        int base = blockIdx.x * HD_NPB + it * 8;
        if (base >= N_NODES) break;
        for (int i = tid; i < 8 * H; i += 256) {
            int nn = base + (i >> 6);
            if (nn < N_NODES) sh[i >> 6][i & 63] = h[(size_t)nn * H + (i & 63)];
        }
        __syncthreads();
        int n = base + sub;
        if (n < N_NODES) {
            float mu = bbmu, lv = bblv;
#pragma unroll
            for (int j = 0; j < H; j++) {
                float hv = sh[sub][j];
                mu = fmaf(hv, sWmu[j * LAT + lane], mu);
                lv = fmaf(hv, sWlv[j * LAT + lane], lv);
            }
            size_t o = (size_t)n * LAT + lane;
            muws[o] = mu; lvws[o] = lv;
        }
        __syncthreads();
    }
}

// ================= heads part 2: JAX noise + z -> d_ws ======================
// JAX partitionable threefry: counter (0, j); 32-bit draws XOR-fold the two
// output words. [verified R4: absmax 0.0156]
__global__ void heads_z(const float* __restrict__ muws, const float* __restrict__ lvws,
                        float* __restrict__ zws) {
    int i = blockIdx.x * blockDim.x + threadIdx.x;
    if (i >= NZ) return;
    float mu = muws[i], lv = lvws[i];
    uint32_t x0 = 0u, x1 = (uint32_t)i;
    threefry2x32_42(x0, x1);
    uint32_t bits = x0 ^ x1;
    float f = __uint_as_float((bits >> 9) | 0x3F800000u) - 1.0f;
    const float lo = -0.99999994f;
    float u = fmaxf(lo, fmaf(f, 2.0f, lo));
    float noise = 1.41421356237309515f * erfinv_f32(u);
    zws[i] = fmaf(noise, expf(0.5f * lv), mu);
}

// ================= copyout: float4 d_ws -> d_out ============================
__global__ void copyout_k(const float4* __restrict__ zs, const float4* __restrict__ ms,
                          const float4* __restrict__ ls, float4* __restrict__ out) {
    int i = blockIdx.x * blockDim.x + threadIdx.x;
    if (i < F4_PER_ARR) {
        out[i] = zs[i];
        out[F4_PER_ARR + i] = ms[i];
        out[2 * F4_PER_ARR + i] = ls[i];
    }
}

// ================= pool + logits (batch SORTED) =============================
__global__ void pool_logits_k(const float4* __restrict__ z4, const int* __restrict__ batch,
                              const float* __restrict__ Wc, const float* __restrict__ bc,
                              float* __restrict__ out) {
    int g = blockIdx.x;
    int tid = threadIdx.x;
    int sub = tid >> 3, slot = tid & 7;
    __shared__ float4 acc4[32][8];
    __shared__ float emb[LAT];
    int lo = 0, hi = N_NODES;
    while (lo < hi) { int mid = (lo + hi) >> 1; if (batch[mid] < g) lo = mid + 1; else hi = mid; }
    int start = lo;
    hi = N_NODES;
    while (lo < hi) { int mid = (lo + hi) >> 1; if (batch[mid] < g + 1) lo = mid + 1; else hi = mid; }
    int end = lo;
    float4 a = make_float4(0.f, 0.f, 0.f, 0.f);
    for (int n = start + sub; n < end; n += 32) {
        float4 v = z4[(size_t)n * (LAT / 4) + slot];
        a.x += v.x; a.y += v.y; a.z += v.z; a.w += v.w;
    }
    acc4[sub][slot] = a;
    __syncthreads();
    if (tid < 8) {
        float4 s4 = acc4[0][tid];
        for (int k = 1; k < 32; k++) {
            s4.x += acc4[k][tid].x; s4.y += acc4[k][tid].y;
            s4.z += acc4[k][tid].z; s4.w += acc4[k][tid].w;
        }
        float invc = 1.0f / fmaxf((float)(end - start), 1.0f);
        emb[tid * 4 + 0] = s4.x * invc; emb[tid * 4 + 1] = s4.y * invc;
        emb[tid * 4 + 2] = s4.z * invc; emb[tid * 4 + 3] = s4.w * invc;
    }
    __syncthreads();
    if (tid < NC) {
        float r = bc[tid];
#pragma unroll
        for (int l = 0; l < LAT; l++) r = fmaf(emb[l], Wc[l * NC + tid], r);
        out[g * NC + tid] = r;
    }
}

extern "C" void kernel_launch(void* const* d_in, const int* in_sizes, int n_in,
                              void* d_out, int out_size, void* d_ws, size_t ws_size,
                              hipStream_t stream) {
    const float* x     = (const float*)d_in[0];
    const int*   ei    = (const int*)d_in[1];
    const float* ea    = (const float*)d_in[2];
    const int*   batch = (const int*)d_in[3];
    const float* We1   = (const float*)d_in[4];
    const float* be1   = (const float*)d_in[5];
    const float* W11   = (const float*)d_in[6];
    const float* b11   = (const float*)d_in[7];
    const float* W12   = (const float*)d_in[8];
    const float* b12   = (const float*)d_in[9];
    const float* eps1  = (const float*)d_in[10];
    const float* We2   = (const float*)d_in[11];
    const float* be2   = (const float*)d_in[12];
    const float* W21   = (const float*)d_in[13];
    const float* b21   = (const float*)d_in[14];
    const float* W22   = (const float*)d_in[15];
    const float* b22   = (const float*)d_in[16];
    const float* eps2  = (const float*)d_in[17];
    const float* Wmu   = (const float*)d_in[18];
    const float* bmu   = (const float*)d_in[19];
    const float* Wlv   = (const float*)d_in[20];
    const float* blv   = (const float*)d_in[21];
    const float* Wc    = (const float*)d_in[22];
    const float* bc    = (const float*)d_in[23];

    // d_ws layout (floats): [hB 6.4M][hA 6.4M][deg 100K][base 100K][bsum 512]
    //   = 52.0e6 B (proven floor 51.7e6 from R4; allocators round up).
    // overlays: muws/lvws over hA (hA dead after heads_ml... dead after conv2);
    //           zws over hB (dead after heads_ml).
    // eids (1.6M ints) lives in d_out's z region — dead until copyout; d_out
    // READS are clean (R6/R7 pool), only compute-kernel WRITES amplify.
    float* hB   = (float*)d_ws;
    float* hA   = hB + (size_t)N_NODES * H;
    int*   deg  = (int*)(hA + (size_t)N_NODES * H);
    int*   base = deg + N_NODES;
    int*   bsum = base + N_NODES;
    int*   eids = (int*)d_out;
    float* muws = hA;
    float* lvws = hA + (size_t)NZ;
    float* zws  = hB;

    hipMemsetAsync(deg, 0, N_NODES * sizeof(int), stream);

    const int* src = ei;
    const int* dst = ei + N_EDGES;

    // CSR build
    csr_count<<<N_EDGES / 256, 256, 0, stream>>>(dst, deg);
    scan_bsums<<<NBLK, 256, 0, stream>>>(deg, bsum);
    scan_partials<<<1, 512, 0, stream>>>(bsum);
    scan_base<<<NBLK, 256, 0, stream>>>(deg, bsum, base);
    csr_fill<<<N_EDGES / 256, 256, 0, stream>>>(dst, base, eids);

    // convs (gather, no atomics)
    conv1_fused<<<N_NODES / C1F, 256, 0, stream>>>(x, src, ea, eids, base, deg,
                                                   We1, be1, W11, b11, W12, b12, eps1, hA);
    conv2_fused<<<N_NODES / C2F, 256, 0, stream>>>(hA, src, ea, eids, base, deg,
                                                   We2, be2, W21, b21, W22, b22, eps2, hB);

    // heads + outputs
    heads_ml<<<(N_NODES + HD_NPB - 1) / HD_NPB, 256, 0, stream>>>(
        hB, Wmu, bmu, Wlv, blv, muws, lvws);
    heads_z<<<(NZ + 255) / 256, 256, 0, stream>>>(muws, lvws, zws);
    copyout_k<<<(F4_PER_ARR + 255) / 256, 256, 0, stream>>>(
        (const float4*)zws, (const float4*)muws, (const float4*)lvws, (float4*)d_out);
    pool_logits_k<<<NG, 256, 0, stream>>>((const float4*)zws, batch, Wc, bc,
                                          (float*)d_out + 3 * (size_t)NZ);
}